// Round 1
// baseline (2902.997 us; speedup 1.0000x reference)
//
#include <hip/hip_runtime.h>
#include <hip/hip_bf16.h>
#include <math.h>

#define NT 8     // nodes per block
#define RR 56    // real rows = NT*7
#define RP 64    // padded rows

// Fused SolutionCalculatorSurface kernel, fp32 correctness-first baseline.
// Block = 256 threads handles NT=8 nodes for ONE v. Grid = (N/NT, V).
__global__ __launch_bounds__(256, 2)
void scs_fused(const float* __restrict__ centers_g,   // N*3
               const float* __restrict__ enc_g,       // N*64
               const float* __restrict__ enc_n,       // N*128
               const float* __restrict__ nb_pos,      // N*6*3
               const float* __restrict__ normals_g,   // N*3
               const float* __restrict__ nb_norm,     // N*6*3
               const float* __restrict__ areas_g,     // N*1
               const float* __restrict__ nb_area,     // N*6
               const float* __restrict__ W1,          // V*7*256
               const float* __restrict__ b1,          // V*256
               const float* __restrict__ W2,          // V*256*128
               const float* __restrict__ b2,          // V*128
               const float* __restrict__ A1,          // V*320*256
               const float* __restrict__ Ab1,         // V*256
               const float* __restrict__ A2,          // V*256
               const float* __restrict__ Ab2,         // V
               float* __restrict__ out,               // N*V
               int Nn)
{
  const int v  = blockIdx.y;
  const int n0 = blockIdx.x * NT;
  const int t  = threadIdx.x;

  __shared__ float feat[RP][8];        // 2 KB   row r = j*7+p, 7 dims + pad
  __shared__ float inv_s[NT][8];       // 256 B  1/dist per (node, neighbor)
  __shared__ float encpre[NT][256];    // 8 KB
  __shared__ float h1c[64][RP];        // 16 KB  [o_local][row], transposed
  __shared__ float basisT[128][RP];    // 32 KB  [h][row], transposed
  __shared__ float rowout[RP];         // 256 B

  // ---------------- Phase 0: featurize ----------------
  if (t < RP) {
    float f[8];
    #pragma unroll
    for (int i = 0; i < 8; i++) f[i] = 0.f;
    const int r = t;
    if (r < RR) {
      const int j = r / 7, p = r % 7;
      const int n = n0 + j;
      if (n < Nn) {
        if (p == 0) {
          f[0] = centers_g[(size_t)n*3+0];
          f[1] = centers_g[(size_t)n*3+1];
          f[2] = centers_g[(size_t)n*3+2];
          f[3] = normals_g[(size_t)n*3+0];
          f[4] = normals_g[(size_t)n*3+1];
          f[5] = normals_g[(size_t)n*3+2];
          f[6] = logf(areas_g[n]) * 0.1f;
        } else {
          const int s = p - 1;
          const float* mp = nb_pos  + ((size_t)n*6 + s)*3;
          const float* mn = nb_norm + ((size_t)n*6 + s)*3;
          f[0] = mp[0] + 1e-6f; f[1] = mp[1] + 1e-6f; f[2] = mp[2] + 1e-6f;
          f[3] = mn[0] + 1e-6f; f[4] = mn[1] + 1e-6f; f[5] = mn[2] + 1e-6f;
          f[6] = logf(nb_area[(size_t)n*6 + s]) * 0.1f + 1e-6f;
        }
      }
    }
    #pragma unroll
    for (int i = 0; i < 8; i++) feat[r][i] = f[i];
  }
  __syncthreads();

  // 1/dist  (center feature minus neighbor feature, 7 dims)
  if (t < NT*6) {
    const int j = t / 6, s = t % 6;
    float d2 = 0.f;
    #pragma unroll
    for (int i = 0; i < 7; i++) {
      const float d = feat[j*7][i] - feat[j*7 + 1 + s][i];
      d2 += d*d;
    }
    inv_s[j][s] = 1.f / sqrtf(d2);
  }

  // ---------------- Phase 1: enc_pre[j][o] ----------------
  // o = t. Encoding reads are wave-uniform -> scalar loads. Weight reads coalesced.
  {
    float acc[NT];
    const float bias = Ab1[v*256 + t];
    #pragma unroll
    for (int j = 0; j < NT; j++) acc[j] = bias;

    // clamped (uniform) node indices for safety
    int nj[NT];
    #pragma unroll
    for (int j = 0; j < NT; j++) {
      int n = n0 + j; if (n >= Nn) n = Nn - 1;
      nj[j] = n;
    }

    const float* a1n = A1 + ((size_t)v*320 + 128)*256 + t;
    for (int i = 0; i < 128; i++) {
      const float w = a1n[(size_t)i * 256];
      #pragma unroll
      for (int j = 0; j < NT; j++)
        acc[j] += enc_n[(size_t)nj[j]*128 + i] * w;
    }
    const float* a1g = A1 + ((size_t)v*320 + 256)*256 + t;
    for (int i = 0; i < 64; i++) {
      const float w = a1g[(size_t)i * 256];
      #pragma unroll
      for (int j = 0; j < NT; j++)
        acc[j] += enc_g[(size_t)nj[j]*64 + i] * w;
    }
    #pragma unroll
    for (int j = 0; j < NT; j++) encpre[j][t] = acc[j];
  }
  __syncthreads();

  // ---------------- Phase 2: H1 (7->256, relu) then BASIS (256->128) ----------------
  const int lane_r = t & 63;                                   // row for h1 compute
  const int wv = __builtin_amdgcn_readfirstlane(t >> 6);       // wave id 0..3 (SGPR)
  float myfeat[7];
  #pragma unroll
  for (int i = 0; i < 7; i++) myfeat[i] = feat[lane_r][i];

  const int cg = t & 15;   // basis col group: h in [cg*8, cg*8+8)
  const int rg = t >> 4;   // basis row group: r in [rg*4, rg*4+4)
  float accb[4][8];
  {
    const float* b2p = b2 + v*128;
    #pragma unroll
    for (int c = 0; c < 8; c++) {
      const float bb = b2p[cg*8 + c];
      #pragma unroll
      for (int k = 0; k < 4; k++) accb[k][c] = bb;
    }
  }
  const float* w1p = W1 + (size_t)v*7*256;
  const float* b1p = b1 + (size_t)v*256;
  const float* w2p = W2 + (size_t)v*256*128;

  for (int ch = 0; ch < 4; ++ch) {
    const int obase = ch * 64;
    // h1 for o in [obase, obase+64): this thread covers o = obase + wv*16 + k
    #pragma unroll
    for (int k = 0; k < 16; k++) {
      const int o = obase + wv*16 + k;            // wave-uniform -> s_load weights
      float h = b1p[o];
      #pragma unroll
      for (int i = 0; i < 7; i++) h += myfeat[i] * w1p[i*256 + o];
      h1c[wv*16 + k][lane_r] = fmaxf(h, 0.f);
    }
    __syncthreads();
    // accumulate BASIS: 32 FMA per (1 ds_read_b128 + 2 global float4)
    for (int ol = 0; ol < 64; ++ol) {
      const int o = obase + ol;
      const float4 wlo = *reinterpret_cast<const float4*>(w2p + (size_t)o*128 + cg*8);
      const float4 whi = *reinterpret_cast<const float4*>(w2p + (size_t)o*128 + cg*8 + 4);
      const float4 hv  = *reinterpret_cast<const float4*>(&h1c[ol][rg*4]);
      const float hvk[4] = {hv.x, hv.y, hv.z, hv.w};
      const float wc[8]  = {wlo.x, wlo.y, wlo.z, wlo.w, whi.x, whi.y, whi.z, whi.w};
      #pragma unroll
      for (int k = 0; k < 4; k++)
        #pragma unroll
        for (int c = 0; c < 8; c++)
          accb[k][c] += hvk[k] * wc[c];
    }
    __syncthreads();
  }
  // write BASIS transposed [h][r]
  #pragma unroll
  for (int c = 0; c < 8; c++) {
    float4 tmp;
    tmp.x = accb[0][c]; tmp.y = accb[1][c]; tmp.z = accb[2][c]; tmp.w = accb[3][c];
    *reinterpret_cast<float4*>(&basisT[cg*8 + c][rg*4]) = tmp;
  }
  __syncthreads();

  // ---------------- Phase 3: H2 = relu(BASIS@A1b + encpre); out = H2@A2 ----------------
  const int og  = t & 15;   // o in [og*16, og*16+16)
  const int rg3 = t >> 4;   // rows [rg3*4, rg3*4+4)
  float acc3[4][16];
  #pragma unroll
  for (int k = 0; k < 4; k++)
    #pragma unroll
    for (int c = 0; c < 16; c++) acc3[k][c] = 0.f;

  const float* a1bp = A1 + (size_t)v*320*256;   // rows 0..127 are A1b
  for (int h = 0; h < 128; ++h) {
    const float4 hv = *reinterpret_cast<const float4*>(&basisT[h][rg3*4]);
    const float* wrow = a1bp + (size_t)h*256 + og*16;
    const float4 w0 = reinterpret_cast<const float4*>(wrow)[0];
    const float4 w1r = reinterpret_cast<const float4*>(wrow)[1];
    const float4 w2r = reinterpret_cast<const float4*>(wrow)[2];
    const float4 w3r = reinterpret_cast<const float4*>(wrow)[3];
    const float hvk[4] = {hv.x, hv.y, hv.z, hv.w};
    const float wc[16] = {w0.x,w0.y,w0.z,w0.w, w1r.x,w1r.y,w1r.z,w1r.w,
                          w2r.x,w2r.y,w2r.z,w2r.w, w3r.x,w3r.y,w3r.z,w3r.w};
    #pragma unroll
    for (int k = 0; k < 4; k++)
      #pragma unroll
      for (int c = 0; c < 16; c++)
        acc3[k][c] += hvk[k] * wc[c];
  }

  // epilogue: add encpre, relu, dot with A2, reduce over o (16 lanes * 16 cols)
  float pacc[4];
  const float* a2p = A2 + v*256;
  #pragma unroll
  for (int k = 0; k < 4; k++) {
    const int r = rg3*4 + k;
    const int j = (r < RR) ? (r / 7) : 0;
    float p = 0.f;
    #pragma unroll
    for (int c = 0; c < 16; c++) {
      const int o = og*16 + c;
      float h2 = acc3[k][c] + encpre[j][o];
      h2 = fmaxf(h2, 0.f);
      p += h2 * a2p[o];
    }
    pacc[k] = p;
  }
  #pragma unroll
  for (int m = 1; m < 16; m <<= 1) {
    #pragma unroll
    for (int k = 0; k < 4; k++) pacc[k] += __shfl_xor(pacc[k], m, 64);
  }
  if (og == 0) {
    #pragma unroll
    for (int k = 0; k < 4; k++) rowout[rg3*4 + k] = pacc[k];
  }
  __syncthreads();

  // ---------------- combine + write ----------------
  if (t < NT) {
    const int n = n0 + t;
    if (n < Nn) {
      const float bias = Ab2[v];
      const float pc = rowout[t*7] + bias;
      float snum = 0.f, sden = 0.f;
      #pragma unroll
      for (int s = 0; s < 6; s++) {
        const float iv = inv_s[t][s];
        snum += (rowout[t*7 + 1 + s] + bias) * iv;
        sden += iv;
      }
      out[(size_t)n*4 + v] = 0.5f * pc + 0.5f * snum / sden;
    }
  }
}

extern "C" void kernel_launch(void* const* d_in, const int* in_sizes, int n_in,
                              void* d_out, int out_size, void* d_ws, size_t ws_size,
                              hipStream_t stream) {
  (void)n_in; (void)out_size; (void)d_ws; (void)ws_size;
  const float* centers = (const float*)d_in[0];
  const float* encg    = (const float*)d_in[1];
  const float* encn    = (const float*)d_in[2];
  const float* nbpos   = (const float*)d_in[3];
  const float* normals = (const float*)d_in[4];
  const float* nbnorm  = (const float*)d_in[5];
  const float* areas   = (const float*)d_in[6];
  const float* nbarea  = (const float*)d_in[7];
  // d_in[8], d_in[9]: global params (unused by reference)
  const float* W1  = (const float*)d_in[10];
  const float* b1  = (const float*)d_in[11];
  const float* W2  = (const float*)d_in[12];
  const float* b2  = (const float*)d_in[13];
  const float* A1  = (const float*)d_in[14];
  const float* Ab1 = (const float*)d_in[15];
  const float* A2  = (const float*)d_in[16];
  const float* Ab2 = (const float*)d_in[17];
  float* out = (float*)d_out;

  const int Nn = in_sizes[0] / 3;              // 30000
  dim3 grid((Nn + NT - 1) / NT, 4);
  hipLaunchKernelGGL(scs_fused, grid, dim3(256), 0, stream,
                     centers, encg, encn, nbpos, normals, nbnorm, areas, nbarea,
                     W1, b1, W2, b2, A1, Ab1, A2, Ab2, out, Nn);
}

// Round 2
// 454.213 us; speedup vs baseline: 6.3913x; 6.3913x over previous
//
#include <hip/hip_runtime.h>
#include <hip/hip_bf16.h>
#include <math.h>

#define NT 16     // nodes per block
#define RR 112    // real rows = NT*7
#define RP 128    // padded rows (M)

typedef __attribute__((ext_vector_type(8))) short bf16x8;
typedef __attribute__((ext_vector_type(4))) float f32x4;

// ws layout (bf16 elements)
#define W1T_OFF 0
#define W1T_ELEMS (4*256*40)              // [v][o][i] i padded 7->40 (K=32 used)
#define W2T_OFF (W1T_OFF + W1T_ELEMS)
#define W2T_ELEMS (4*128*264)             // [v][h][o] o padded 256->264
#define A1T_OFF (W2T_OFF + W2T_ELEMS)
#define A1T_ELEMS (4*256*328)             // [v][h][i] i padded 320->328
#define WS_ELEMS (A1T_OFF + A1T_ELEMS)    // 512000 elems = 1,024,000 B

__device__ __forceinline__ unsigned short f2b(float f) {
  union { float f; unsigned u; } x; x.f = f;
  unsigned r = x.u + 0x7fffu + ((x.u >> 16) & 1u);   // RNE
  return (unsigned short)(r >> 16);
}
__device__ __forceinline__ float b2f(unsigned short h) {
  union { unsigned u; float f; } x; x.u = ((unsigned)h) << 16; return x.f;
}

// ---------- prep: transpose+convert weights to bf16 in ws ----------
__global__ void scs_prep(const float* __restrict__ W1, const float* __restrict__ W2,
                         const float* __restrict__ A1, unsigned short* __restrict__ ws) {
  for (int e = blockIdx.x * 256 + threadIdx.x; e < WS_ELEMS; e += gridDim.x * 256) {
    unsigned short val;
    if (e < W2T_OFF) {                       // W1T[v][o][i]
      int r = e;            int v = r / (256*40); r %= (256*40);
      int o = r / 40, i = r % 40;
      val = (i < 7) ? f2b(W1[((size_t)v*7 + i)*256 + o]) : (unsigned short)0;
    } else if (e < A1T_OFF) {                // W2T[v][h][o]
      int r = e - W2T_OFF;  int v = r / (128*264); r %= (128*264);
      int h = r / 264, o = r % 264;
      val = (o < 256) ? f2b(W2[((size_t)v*256 + o)*128 + h]) : (unsigned short)0;
    } else {                                 // A1T[v][h][i]
      int r = e - A1T_OFF;  int v = r / (256*328); r %= (256*328);
      int h = r / 328, i = r % 328;
      val = (i < 320) ? f2b(A1[((size_t)v*320 + i)*256 + h]) : (unsigned short)0;
    }
    ws[e] = val;
  }
}

// ---------- main fused kernel ----------
__global__ __launch_bounds__(256, 2)
void scs_fused(const float* __restrict__ centers_g,   // N*3
               const float* __restrict__ enc_g,       // N*64
               const float* __restrict__ enc_n,       // N*128
               const float* __restrict__ nb_pos,      // N*6*3
               const float* __restrict__ normals_g,   // N*3
               const float* __restrict__ nb_norm,     // N*6*3
               const float* __restrict__ areas_g,     // N*1
               const float* __restrict__ nb_area,     // N*6
               const unsigned short* __restrict__ ws, // bf16 weights
               const float* __restrict__ b1,          // V*256
               const float* __restrict__ b2,          // V*128
               const float* __restrict__ Ab1,         // V*256
               const float* __restrict__ A2,          // V*256
               const float* __restrict__ Ab2,         // V
               float* __restrict__ out,               // N*4 (n-major, v fastest)
               int Nn)
{
  const int v  = blockIdx.y;
  const int n0 = blockIdx.x * NT;
  const int t  = threadIdx.x;
  const int lane = t & 63;
  const int wv = t >> 6;       // wave 0..3
  const int lr = lane & 15;    // row/col lane id within tile
  const int lk = lane >> 4;    // k-group 0..3

  __shared__ unsigned short featb[RP * 40];   // 10.2 KB  [row][i], K=32 used
  __shared__ unsigned short h1s[RP * 72];     // 18.4 KB  [row][o_local 0..64)
  __shared__ unsigned short basis[RP * 136];  // 34.8 KB  [row][h 0..128)
  __shared__ unsigned short encA[NT * 200];   // 6.4 KB   [node][k 0..192)
  __shared__ float inv_s[NT][8];
  __shared__ float rowpart[4][RP];

  // ---------- Phase 0: featurize + encA fill ----------
  for (int e = t; e < NT * 192; e += 256) {
    int row = e / 192, c = e % 192;
    int n = n0 + row; if (n >= Nn) n = Nn - 1;
    float val = (c < 128) ? enc_n[(size_t)n * 128 + c] : enc_g[(size_t)n * 64 + (c - 128)];
    encA[row * 200 + c] = f2b(val);
  }
  if (t < RP) {
    float f[8];
    #pragma unroll
    for (int i = 0; i < 8; i++) f[i] = 0.f;
    const int r = t;
    if (r < RR) {
      const int j = r / 7, p = r % 7;
      const int n = n0 + j;
      if (n < Nn) {
        if (p == 0) {
          f[0] = centers_g[(size_t)n*3+0]; f[1] = centers_g[(size_t)n*3+1]; f[2] = centers_g[(size_t)n*3+2];
          f[3] = normals_g[(size_t)n*3+0]; f[4] = normals_g[(size_t)n*3+1]; f[5] = normals_g[(size_t)n*3+2];
          f[6] = logf(areas_g[n]) * 0.1f;
        } else {
          const int s = p - 1;
          const float* mp = nb_pos  + ((size_t)n*6 + s)*3;
          const float* mn = nb_norm + ((size_t)n*6 + s)*3;
          f[0] = mp[0] + 1e-6f; f[1] = mp[1] + 1e-6f; f[2] = mp[2] + 1e-6f;
          f[3] = mn[0] + 1e-6f; f[4] = mn[1] + 1e-6f; f[5] = mn[2] + 1e-6f;
          f[6] = logf(nb_area[(size_t)n*6 + s]) * 0.1f + 1e-6f;
        }
      }
    }
    unsigned* fb32 = reinterpret_cast<unsigned*>(featb);
    #pragma unroll
    for (int i = 0; i < 4; i++) {
      unsigned lo = f2b(f[2*i]), hi = f2b(f[2*i+1]);
      fb32[r * 20 + i] = lo | (hi << 16);
    }
    #pragma unroll
    for (int i = 4; i < 20; i++) fb32[r * 20 + i] = 0;
  }
  __syncthreads();

  // 1/dist from bf16 features (7 dims)
  if (t < NT * 6) {
    const int j = t / 6, s = t % 6;
    float d2 = 0.f;
    #pragma unroll
    for (int i = 0; i < 7; i++) {
      const float d = b2f(featb[(j*7)*40 + i]) - b2f(featb[(j*7 + 1 + s)*40 + i]);
      d2 += d * d;
    }
    inv_s[j][s] = 1.f / sqrtf(d2);
  }

  // ---------- Phase 1: H1 (MFMA) + BASIS accumulate, 4 chunks of 64 o's ----------
  f32x4 accB[8][2];
  {
    #pragma unroll
    for (int nt = 0; nt < 2; ++nt) {
      const float bb = b2[v*128 + wv*32 + nt*16 + lr];
      #pragma unroll
      for (int mt = 0; mt < 8; ++mt) accB[mt][nt] = (f32x4){bb, bb, bb, bb};
    }
  }
  const unsigned short* w1t = ws + W1T_OFF + (size_t)v * 256 * 40;
  const unsigned short* w2t = ws + W2T_OFF + (size_t)v * 128 * 264;

  for (int ch = 0; ch < 4; ++ch) {
    // H1: this wave computes o-tile [ch*64 + wv*16, +16)
    {
      const int obase = ch*64 + wv*16;
      const bf16x8 bfrag = *(const bf16x8*)(w1t + (size_t)(obase + lr)*40 + lk*8);
      const float b1c = b1[v*256 + obase + lr];
      #pragma unroll
      for (int mt = 0; mt < 8; ++mt) {
        const bf16x8 afrag = *(const bf16x8*)&featb[(mt*16 + lr)*40 + lk*8];
        f32x4 c = (f32x4){b1c, b1c, b1c, b1c};
        c = __builtin_amdgcn_mfma_f32_16x16x32_bf16(afrag, bfrag, c, 0, 0, 0);
        #pragma unroll
        for (int g = 0; g < 4; ++g)
          h1s[(mt*16 + lk*4 + g)*72 + wv*16 + lr] = f2b(fmaxf(c[g], 0.f));
      }
    }
    __syncthreads();
    // BASIS accumulate over this chunk's K=64 (2 ksteps)
    #pragma unroll
    for (int ks = 0; ks < 2; ++ks) {
      bf16x8 bf[2];
      #pragma unroll
      for (int nt = 0; nt < 2; ++nt)
        bf[nt] = *(const bf16x8*)(w2t + (size_t)(wv*32 + nt*16 + lr)*264 + ch*64 + ks*32 + lk*8);
      #pragma unroll
      for (int mt = 0; mt < 8; ++mt) {
        const bf16x8 af = *(const bf16x8*)&h1s[(mt*16 + lr)*72 + ks*32 + lk*8];
        accB[mt][0] = __builtin_amdgcn_mfma_f32_16x16x32_bf16(af, bf[0], accB[mt][0], 0, 0, 0);
        accB[mt][1] = __builtin_amdgcn_mfma_f32_16x16x32_bf16(af, bf[1], accB[mt][1], 0, 0, 0);
      }
    }
    __syncthreads();
  }

  // ---------- Phase 2: basis writeback (no activation) ----------
  #pragma unroll
  for (int mt = 0; mt < 8; ++mt)
    #pragma unroll
    for (int nt = 0; nt < 2; ++nt)
      #pragma unroll
      for (int g = 0; g < 4; ++g)
        basis[(mt*16 + lk*4 + g)*136 + wv*32 + nt*16 + lr] = f2b(accB[mt][nt][g]);
  __syncthreads();

  // ---------- Phase 3: H2 fused K=320 = [basis(128) | enc(192)] ----------
  f32x4 accH[8][4];
  const int nbase = wv * 64;   // this wave's N strip (4 tiles)
  {
    #pragma unroll
    for (int nt = 0; nt < 4; ++nt) {
      const float ab = Ab1[v*256 + nbase + nt*16 + lr];
      #pragma unroll
      for (int mt = 0; mt < 8; ++mt) accH[mt][nt] = (f32x4){ab, ab, ab, ab};
    }
  }
  int jrow[8];
  #pragma unroll
  for (int mt = 0; mt < 8; ++mt) {
    int row = mt*16 + lr;
    int j = row / 7; if (j > NT-1) j = NT-1;
    jrow[mt] = j;
  }
  const unsigned short* a1t = ws + A1T_OFF + (size_t)v * 256 * 328;
  // K part 1: basis (ks 0..3)
  #pragma unroll
  for (int ks = 0; ks < 4; ++ks) {
    bf16x8 bf[4];
    #pragma unroll
    for (int nt = 0; nt < 4; ++nt)
      bf[nt] = *(const bf16x8*)(a1t + (size_t)(nbase + nt*16 + lr)*328 + ks*32 + lk*8);
    #pragma unroll
    for (int mt = 0; mt < 8; ++mt) {
      const bf16x8 af = *(const bf16x8*)&basis[(mt*16 + lr)*136 + ks*32 + lk*8];
      #pragma unroll
      for (int nt = 0; nt < 4; ++nt)
        accH[mt][nt] = __builtin_amdgcn_mfma_f32_16x16x32_bf16(af, bf[nt], accH[mt][nt], 0, 0, 0);
    }
  }
  // K part 2: enc (ks 4..9), A rows map row -> node j
  #pragma unroll
  for (int ks = 0; ks < 6; ++ks) {
    bf16x8 bf[4];
    #pragma unroll
    for (int nt = 0; nt < 4; ++nt)
      bf[nt] = *(const bf16x8*)(a1t + (size_t)(nbase + nt*16 + lr)*328 + (4 + ks)*32 + lk*8);
    #pragma unroll
    for (int mt = 0; mt < 8; ++mt) {
      const bf16x8 af = *(const bf16x8*)&encA[jrow[mt]*200 + ks*32 + lk*8];
      #pragma unroll
      for (int nt = 0; nt < 4; ++nt)
        accH[mt][nt] = __builtin_amdgcn_mfma_f32_16x16x32_bf16(af, bf[nt], accH[mt][nt], 0, 0, 0);
    }
  }

  // ---------- Phase 4: epilogue — relu, dot A2, reduce over N ----------
  {
    float a2c[4];
    #pragma unroll
    for (int nt = 0; nt < 4; ++nt) a2c[nt] = A2[v*256 + nbase + nt*16 + lr];
    #pragma unroll
    for (int mt = 0; mt < 8; ++mt) {
      #pragma unroll
      for (int g = 0; g < 4; ++g) {
        float s = 0.f;
        #pragma unroll
        for (int nt = 0; nt < 4; ++nt)
          s += fmaxf(accH[mt][nt][g], 0.f) * a2c[nt];
        s += __shfl_xor(s, 1); s += __shfl_xor(s, 2);
        s += __shfl_xor(s, 4); s += __shfl_xor(s, 8);
        if (lr == 0) rowpart[wv][mt*16 + lk*4 + g] = s;
      }
    }
  }
  __syncthreads();

  // ---------- Phase 5: combine + write ----------
  if (t < NT) {
    const int n = n0 + t;
    if (n < Nn) {
      const float ab2v = Ab2[v];
      float pt[7];
      #pragma unroll
      for (int p = 0; p < 7; ++p)
        pt[p] = rowpart[0][t*7+p] + rowpart[1][t*7+p] + rowpart[2][t*7+p] + rowpart[3][t*7+p] + ab2v;
      float snum = 0.f, sden = 0.f;
      #pragma unroll
      for (int s6 = 0; s6 < 6; ++s6) {
        const float iv = inv_s[t][s6];
        snum += pt[1 + s6] * iv; sden += iv;
      }
      out[(size_t)n*4 + v] = 0.5f * pt[0] + 0.5f * snum / sden;
    }
  }
}

extern "C" void kernel_launch(void* const* d_in, const int* in_sizes, int n_in,
                              void* d_out, int out_size, void* d_ws, size_t ws_size,
                              hipStream_t stream) {
  (void)n_in; (void)out_size; (void)ws_size;
  const float* centers = (const float*)d_in[0];
  const float* encg    = (const float*)d_in[1];
  const float* encn    = (const float*)d_in[2];
  const float* nbpos   = (const float*)d_in[3];
  const float* normals = (const float*)d_in[4];
  const float* nbnorm  = (const float*)d_in[5];
  const float* areas   = (const float*)d_in[6];
  const float* nbarea  = (const float*)d_in[7];
  const float* W1  = (const float*)d_in[10];
  const float* b1  = (const float*)d_in[11];
  const float* W2  = (const float*)d_in[12];
  const float* b2  = (const float*)d_in[13];
  const float* A1  = (const float*)d_in[14];
  const float* Ab1 = (const float*)d_in[15];
  const float* A2  = (const float*)d_in[16];
  const float* Ab2 = (const float*)d_in[17];
  float* out = (float*)d_out;
  unsigned short* ws = (unsigned short*)d_ws;

  const int Nn = in_sizes[0] / 3;   // 30000

  hipLaunchKernelGGL(scs_prep, dim3(2000), dim3(256), 0, stream, W1, W2, A1, ws);

  dim3 grid((Nn + NT - 1) / NT, 4);
  hipLaunchKernelGGL(scs_fused, grid, dim3(256), 0, stream,
                     centers, encg, encn, nbpos, normals, nbnorm, areas, nbarea,
                     ws, b1, b2, Ab1, A2, Ab2, out, Nn);
}